// Round 3
// baseline (400.916 us; speedup 1.0000x reference)
//
#include <hip/hip_runtime.h>

#define BB 512
#define TT 512
#define KK 64
#define WPB 4
#define IPW 16   // from-tags per wave

// lgkm-only barrier: keeps global_load_lds transfers in flight across it
// (__syncthreads would drain vmcnt(0) and expose HBM latency every step)
#define BARRIER()  asm volatile("s_waitcnt lgkmcnt(0)\n\ts_barrier" ::: "memory")
#define WAIT_VM0() asm volatile("s_waitcnt vmcnt(0)" ::: "memory")

__device__ __forceinline__ void gl_lds16(const float* g, float* l) {
    // 16B/lane async global->LDS; LDS dest = uniform base + lane*16
    __builtin_amdgcn_global_load_lds((const __attribute__((address_space(1))) void*)g,
                                     (__attribute__((address_space(3))) void*)l, 16, 0, 0);
}

__global__ __launch_bounds__(256, 2) void crf_kernel(const float* __restrict__ pot,
                                                     const float* __restrict__ trans,
                                                     int* __restrict__ out) {
    __shared__ unsigned char bp[TT][KK];       // 32 KB backpointers
    __shared__ int2 ex[2][WPB][KK + 2];        // padded: 2-way bank aliasing only (free)
    __shared__ float stage[2][32 * KK];        // 16 KB pot staging, 32 steps/chunk
    __shared__ int wsum[WPB];
    __shared__ unsigned char bnd[KK];          // segment-boundary tags

    const int b = blockIdx.x;
    const int tid = threadIdx.x;
    const int lane = tid & 63;
    const int w = tid >> 6;
    const int i0 = w * IPW;
    const float* pb = pot + (size_t)b * TT * KK;

    // ---- issue staging of chunks 0,1 (latency hidden under count phase) ----
    {
        const float* g0 = pb + (w * 8) * KK;
        float* l0 = &stage[0][w * 8 * KK];
        gl_lds16(g0 + lane * 4, l0);
        gl_lds16(g0 + 256 + lane * 4, l0 + 256);
        const float* g1 = pb + (32 + w * 8) * KK;
        float* l1 = &stage[1][w * 8 * KK];
        gl_lds16(g1 + lane * 4, l1);
        gl_lds16(g1 + 256 + lane * 4, l1 + 256);
    }

    // ---- fused seq-len count: nonzeros in this batch's [T,K] slab, >> 6 ----
    int cnt = 0;
    {
        const float4* p4 = (const float4*)pb;
        #pragma unroll 8
        for (int r = 0; r < 32; ++r) {
            float4 v = p4[tid + 256 * r];
            cnt += (v.x != 0.f) + (v.y != 0.f) + (v.z != 0.f) + (v.w != 0.f);
        }
        #pragma unroll
        for (int off = 32; off > 0; off >>= 1) cnt += __shfl_down(cnt, off, 64);
        if (lane == 0) wsum[w] = cnt;
        BARRIER();
    }
    const int seqlen = (wsum[0] + wsum[1] + wsum[2] + wsum[3]) >> 6;

    // trans column 'lane' for this wave's i-range
    float tc[IPW];
    #pragma unroll
    for (int q = 0; q < IPW; ++q) tc[q] = trans[(i0 + q) * KK + lane];

    float alpha = pb[lane];

    WAIT_VM0();   // chunks 0,1 resident
    BARRIER();    // ... for ALL waves' staging

    // ------------------------------ forward ------------------------------
    for (int t = 1; t < TT; ++t) {
        if ((t & 31) == 0) {                 // entering chunk c = t>>5
            WAIT_VM0();                      // own staging of chunk c done
            BARRIER();                       // rendezvous: everyone's staging done
            const int cn = (t >> 5) + 1;
            if (cn < 16) {
                const float* g0 = pb + (cn * 32 + w * 8) * KK;
                float* l0 = &stage[cn & 1][w * 8 * KK];
                gl_lds16(g0 + lane * 4, l0);
                gl_lds16(g0 + 256 + lane * 4, l0 + 256);
            }
        }
        const float ptj = stage[(t >> 5) & 1][(t & 31) * KK + lane];

        // partial max/argmax over this wave's 16 i's (4 chunks of 4, strict >)
        float m[4]; int am[4];
        #pragma unroll
        for (int c = 0; c < 4; ++c) {
            const int base = i0 + c * 4;
            float ai = __int_as_float(__builtin_amdgcn_readlane(__float_as_int(alpha), base));
            m[c] = ai + tc[c * 4];
            am[c] = base;
            #pragma unroll
            for (int qq = 1; qq < 4; ++qq) {
                const int iq = base + qq;
                float aq = __int_as_float(__builtin_amdgcn_readlane(__float_as_int(alpha), iq));
                float s = aq + tc[c * 4 + qq];
                bool g = s > m[c];
                m[c] = g ? s : m[c];
                am[c] = g ? iq : am[c];
            }
        }
        bool g01 = m[1] > m[0]; float m01 = g01 ? m[1] : m[0]; int a01 = g01 ? am[1] : am[0];
        bool g23 = m[3] > m[2]; float m23 = g23 ? m[3] : m[2]; int a23 = g23 ? am[3] : am[2];
        bool gg  = m23 > m01;  float mw  = gg ? m23 : m01;    int aw  = gg ? a23 : a01;

        const int buf = t & 1;
        ex[buf][w][lane] = make_int2(__float_as_int(mw), aw);
        BARRIER();
        const int2 e0 = ex[buf][0][lane], e1 = ex[buf][1][lane];
        const int2 e2 = ex[buf][2][lane], e3 = ex[buf][3][lane];
        const float f0 = __int_as_float(e0.x), f1 = __int_as_float(e1.x);
        const float f2 = __int_as_float(e2.x), f3 = __int_as_float(e3.x);
        bool h01 = f1 > f0; float p01 = h01 ? f1 : f0; int q01 = h01 ? e1.y : e0.y;
        bool h23 = f3 > f2; float p23 = h23 ? f3 : f2; int q23 = h23 ? e3.y : e2.y;
        bool hh  = p23 > p01; float M = hh ? p23 : p01; int BI = hh ? q23 : q01;

        const bool valid = (t < seqlen);
        alpha = valid ? (ptj + M) : alpha;
        if (w == (t & 3)) bp[t][lane] = (unsigned char)(valid ? BI : lane);  // rotate writer
    }

    BARRIER();    // all bp writes visible to wave 0

    // -------------------- backtrace (wave 0 only) --------------------
    if (w == 0) {
        // final argmax, first-occurrence ties
        float v = alpha; int idx = lane;
        #pragma unroll
        for (int off = 1; off < 64; off <<= 1) {
            float vo = __shfl_xor(v, off, 64);
            int io  = __shfl_xor(idx, off, 64);
            bool take = (vo > v) || (vo == v && io < idx);
            v = take ? vo : v;
            idx = take ? io : idx;
        }
        const int last_tag = idx;

        // phase A: 64 segment maps of 8 steps each; lane e computes
        // cur[s] = tag at time 8s given tag e at time 8(s+1) (s=63: from 511)
        int cur[64];
        #pragma unroll
        for (int s = 0; s < 64; ++s) cur[s] = lane;
        #pragma unroll
        for (int h = 8; h >= 1; --h) {
            #pragma unroll
            for (int s = 0; s < 64; ++s) {
                if (h == 8 && s == 63) continue;   // t=512 doesn't exist
                cur[s] = bp[8 * s + h][cur[s]];
            }
        }
        // phase B: stitch boundaries via dynamic-lane readlane (uniform chain)
        // bnd[s] = tag at end of segment s (time 8s+8; s=63 -> time 511)
        int tag = last_tag;
        bnd[63] = (unsigned char)last_tag;
        #pragma unroll
        for (int s = 63; s >= 1; --s) {
            tag = __builtin_amdgcn_readlane(cur[s], tag);
            bnd[s - 1] = (unsigned char)tag;
        }
        // phase C: lane s reconstructs its segment's tags
        int cc = bnd[lane];
        const int t0 = lane * 8;
        int* ob = out + b * TT;
        if (lane == 63) ob[TT - 1] = last_tag;
        if (lane < 63) {
            cc = bp[t0 + 8][cc];
            ob[t0 + 7] = cc;
        }
        #pragma unroll
        for (int h = 7; h >= 1; --h) {
            cc = bp[t0 + h][cc];
            ob[t0 + h - 1] = cc;
        }
    }
}

extern "C" void kernel_launch(void* const* d_in, const int* in_sizes, int n_in,
                              void* d_out, int out_size, void* d_ws, size_t ws_size,
                              hipStream_t stream) {
    const float* inp = (const float*)d_in[0];     // [B, T, K] fp32
    const float* trans = (const float*)d_in[1];   // [K, K] fp32
    int* out = (int*)d_out;                       // [B, T] int32
    crf_kernel<<<BB, 256, 0, stream>>>(inp, trans, out);
}

// Round 4
// 333.573 us; speedup vs baseline: 1.2019x; 1.2019x over previous
//
#include <hip/hip_runtime.h>

#define BB 512
#define TT 512
#define KK 64

typedef float v2f __attribute__((ext_vector_type(2)));

__device__ __forceinline__ float frl(float v, int lane) {
    return __int_as_float(__builtin_amdgcn_readlane(__float_as_int(v), lane));
}
__device__ __forceinline__ v2f vmax2(v2f a, v2f b) {
    v2f r; r.x = fmaxf(a.x, b.x); r.y = fmaxf(a.y, b.y); return r;
}
// wave-wide unsigned max; result valid in lane 63 (canonical gfx9 DPP sequence)
__device__ __forceinline__ unsigned wave_umax63(unsigned x) {
    unsigned d;
    d = (unsigned)__builtin_amdgcn_update_dpp((int)x, (int)x, 0x111, 0xF, 0xF, false); x = x > d ? x : d;
    d = (unsigned)__builtin_amdgcn_update_dpp((int)x, (int)x, 0x112, 0xF, 0xF, false); x = x > d ? x : d;
    d = (unsigned)__builtin_amdgcn_update_dpp((int)x, (int)x, 0x114, 0xF, 0xF, false); x = x > d ? x : d;
    d = (unsigned)__builtin_amdgcn_update_dpp((int)x, (int)x, 0x118, 0xF, 0xF, false); x = x > d ? x : d;
    d = (unsigned)__builtin_amdgcn_update_dpp((int)x, (int)x, 0x142, 0xA, 0xF, false); x = x > d ? x : d;
    d = (unsigned)__builtin_amdgcn_update_dpp((int)x, (int)x, 0x143, 0xC, 0xF, false); x = x > d ? x : d;
    return x;
}

// ---------------------------------------------------------------------------
// seq_lens[b] = nonzero_count >> 6 (fp32-exact in reference; proven in R1)
// ---------------------------------------------------------------------------
__global__ __launch_bounds__(256) void seqlen_kernel(const float* __restrict__ inp,
                                                     int* __restrict__ seq_lens) {
    int b = blockIdx.x;
    int tid = threadIdx.x;
    const float4* p4 = (const float4*)(inp + (size_t)b * TT * KK);
    const int n4 = TT * KK / 4;
    int cnt = 0;
    for (int idx = tid; idx < n4; idx += 256) {
        float4 v = p4[idx];
        cnt += (v.x != 0.0f) + (v.y != 0.0f) + (v.z != 0.0f) + (v.w != 0.0f);
    }
    #pragma unroll
    for (int off = 32; off > 0; off >>= 1) cnt += __shfl_down(cnt, off, 64);
    __shared__ int wsum[4];
    if ((tid & 63) == 0) wsum[tid >> 6] = cnt;
    __syncthreads();
    if (tid == 0) seq_lens[b] = (wsum[0] + wsum[1] + wsum[2] + wsum[3]) >> 6;
}

// ---------------------------------------------------------------------------
// Fast path: max-only forward (alpha history -> global ws), then per-wave
// backtrace by exact recomputation + DPP-max + ballot first-match.
// One wave per batch; 2 waves per block (shared transT staging).
// ---------------------------------------------------------------------------
__global__ __launch_bounds__(128) void fwd_kernel(const float* __restrict__ pot,
                                                  const float* __restrict__ trans,
                                                  const int* __restrict__ seq_lens,
                                                  float* __restrict__ alphaH,
                                                  int* __restrict__ out) {
    __shared__ float tT[KK][KK + 1];   // tT[j][i] = trans[i][j], padded (conflict-free)

    const int lane = threadIdx.x & 63;
    const int w = threadIdx.x >> 6;
    const int b = blockIdx.x * 2 + w;

    // stage transposed transitions (coalesced global reads)
    for (int r = w * 32; r < w * 32 + 32; ++r) tT[lane][r] = trans[r * KK + lane];
    __syncthreads();

    const int seqlen = seq_lens[b];
    const float* pb = pot + (size_t)b * TT * KK;
    float* hb = alphaH + (size_t)b * TT * KK;
    int* ob = out + b * TT;

    // forward trans pairs: tc2[k] = {trans[2k][lane], trans[2k+1][lane]}
    v2f tc2[32];
    #pragma unroll
    for (int k = 0; k < 32; ++k) {
        v2f t2; t2.x = trans[(2 * k) * KK + lane]; t2.y = trans[(2 * k + 1) * KK + lane];
        tc2[k] = t2;
    }

    float alpha = pb[lane];
    hb[lane] = alpha;

    // ---------------- forward: max-plus, no argmax ----------------
    float pf0 = pb[1 * KK + lane], pf1 = pb[2 * KK + lane], pf2 = pb[3 * KK + lane],
          pf3 = pb[4 * KK + lane], pf4 = pb[5 * KK + lane], pf5 = pb[6 * KK + lane],
          pf6 = pb[7 * KK + lane], pf7 = pb[8 * KK + lane];

    auto step = [&](float ptj, int t) {
        v2f a0, a1, a2, a3;
        {
            v2f av;
            av.x = frl(alpha, 0); av.y = frl(alpha, 1); a0 = av + tc2[0];
            av.x = frl(alpha, 2); av.y = frl(alpha, 3); a1 = av + tc2[1];
            av.x = frl(alpha, 4); av.y = frl(alpha, 5); a2 = av + tc2[2];
            av.x = frl(alpha, 6); av.y = frl(alpha, 7); a3 = av + tc2[3];
        }
        #pragma unroll
        for (int k = 4; k < 32; k += 4) {
            v2f av;
            av.x = frl(alpha, 2 * k + 0); av.y = frl(alpha, 2 * k + 1); a0 = vmax2(a0, av + tc2[k + 0]);
            av.x = frl(alpha, 2 * k + 2); av.y = frl(alpha, 2 * k + 3); a1 = vmax2(a1, av + tc2[k + 1]);
            av.x = frl(alpha, 2 * k + 4); av.y = frl(alpha, 2 * k + 5); a2 = vmax2(a2, av + tc2[k + 2]);
            av.x = frl(alpha, 2 * k + 6); av.y = frl(alpha, 2 * k + 7); a3 = vmax2(a3, av + tc2[k + 3]);
        }
        v2f mm = vmax2(vmax2(a0, a1), vmax2(a2, a3));
        float M = fmaxf(mm.x, mm.y);
        alpha = (t < seqlen) ? (ptj + M) : alpha;
        hb[t * KK + lane] = alpha;
    };

    for (int c = 0; c < 63; ++c) {
        const int t0 = 1 + 8 * c;
        step(pf0, t0 + 0); { int tn = t0 + 8;  tn = tn > 511 ? 511 : tn; pf0 = pb[tn * KK + lane]; }
        step(pf1, t0 + 1); { int tn = t0 + 9;  tn = tn > 511 ? 511 : tn; pf1 = pb[tn * KK + lane]; }
        step(pf2, t0 + 2); { int tn = t0 + 10; tn = tn > 511 ? 511 : tn; pf2 = pb[tn * KK + lane]; }
        step(pf3, t0 + 3); { int tn = t0 + 11; tn = tn > 511 ? 511 : tn; pf3 = pb[tn * KK + lane]; }
        step(pf4, t0 + 4); { int tn = t0 + 12; tn = tn > 511 ? 511 : tn; pf4 = pb[tn * KK + lane]; }
        step(pf5, t0 + 5); { int tn = t0 + 13; tn = tn > 511 ? 511 : tn; pf5 = pb[tn * KK + lane]; }
        step(pf6, t0 + 6); { int tn = t0 + 14; tn = tn > 511 ? 511 : tn; pf6 = pb[tn * KK + lane]; }
        step(pf7, t0 + 7); { int tn = t0 + 15; tn = tn > 511 ? 511 : tn; pf7 = pb[tn * KK + lane]; }
    }
    step(pf0, 505); step(pf1, 506); step(pf2, 507); step(pf3, 508);
    step(pf4, 509); step(pf5, 510); step(pf6, 511);

    // ---------------- final argmax (first occurrence) ----------------
    float v = alpha; int idx = lane;
    #pragma unroll
    for (int off = 1; off < 64; off <<= 1) {
        float vo = __shfl_xor(v, off, 64);
        int io = __shfl_xor(idx, off, 64);
        bool take = (vo > v) || (vo == v && io < idx);
        v = take ? vo : v;
        idx = take ? io : idx;
    }
    int cur = idx;          // uniform
    int slot = cur;         // lane 63's slot = tag at t=511; others overwritten

    // ---------------- backtrace: recompute + DPP-max + ballot ----------------
    float r0 = hb[510 * KK + lane], r1 = hb[509 * KK + lane], r2 = hb[508 * KK + lane],
          r3 = hb[507 * KK + lane], r4 = hb[506 * KK + lane], r5 = hb[505 * KK + lane],
          r6 = hb[504 * KK + lane], r7 = hb[503 * KK + lane];

    auto bt_step = [&](int t, float arow) {
        if (t < seqlen) {
            float cand = arow + tT[cur][lane];
            unsigned u = __float_as_uint(cand);
            u = u ^ ((unsigned)(((int)u) >> 31) | 0x80000000u);   // sortable key
            unsigned run = wave_umax63(u);
            unsigned Umax = (unsigned)__builtin_amdgcn_readlane((int)run, 63);
            unsigned long long mk = __ballot(u == Umax);
            cur = (int)__builtin_ctzll(mk);                        // first i == argmax
        }
        const int tm = t - 1;
        slot = ((tm & 63) == lane) ? cur : slot;
        if ((tm & 63) == 0) ob[tm + lane] = slot;
    };

    int T0 = 511;
    for (int c = 0; c < 63; ++c) {
        bt_step(T0 - 0, r0); { int pi = T0 - 9;  pi = pi < 0 ? 0 : pi; r0 = hb[pi * KK + lane]; }
        bt_step(T0 - 1, r1); { int pi = T0 - 10; pi = pi < 0 ? 0 : pi; r1 = hb[pi * KK + lane]; }
        bt_step(T0 - 2, r2); { int pi = T0 - 11; pi = pi < 0 ? 0 : pi; r2 = hb[pi * KK + lane]; }
        bt_step(T0 - 3, r3); { int pi = T0 - 12; pi = pi < 0 ? 0 : pi; r3 = hb[pi * KK + lane]; }
        bt_step(T0 - 4, r4); { int pi = T0 - 13; pi = pi < 0 ? 0 : pi; r4 = hb[pi * KK + lane]; }
        bt_step(T0 - 5, r5); { int pi = T0 - 14; pi = pi < 0 ? 0 : pi; r5 = hb[pi * KK + lane]; }
        bt_step(T0 - 6, r6); { int pi = T0 - 15; pi = pi < 0 ? 0 : pi; r6 = hb[pi * KK + lane]; }
        bt_step(T0 - 7, r7); { int pi = T0 - 16; pi = pi < 0 ? 0 : pi; r7 = hb[pi * KK + lane]; }
        T0 -= 8;
    }
    // tail: t = 7..1 (rows 6..0 are in r0..r6)
    bt_step(7, r0); bt_step(6, r1); bt_step(5, r2); bt_step(4, r3);
    bt_step(3, r4); bt_step(2, r5); bt_step(1, r6);
}

// ---------------------------------------------------------------------------
// Fallback (proven R3 kernel) — used when ws is too small for alpha history.
// ---------------------------------------------------------------------------
#define WPB 4
#define IPW 16
#define BARRIER()  asm volatile("s_waitcnt lgkmcnt(0)\n\ts_barrier" ::: "memory")
#define WAIT_VM0() asm volatile("s_waitcnt vmcnt(0)" ::: "memory")

__device__ __forceinline__ void gl_lds16(const float* g, float* l) {
    __builtin_amdgcn_global_load_lds((const __attribute__((address_space(1))) void*)g,
                                     (__attribute__((address_space(3))) void*)l, 16, 0, 0);
}

__global__ __launch_bounds__(256, 2) void crf_kernel(const float* __restrict__ pot,
                                                     const float* __restrict__ trans,
                                                     int* __restrict__ out) {
    __shared__ unsigned char bp[TT][KK];
    __shared__ int2 ex[2][WPB][KK + 2];
    __shared__ float stage[2][32 * KK];
    __shared__ int wsum[WPB];
    __shared__ unsigned char bnd[KK];

    const int b = blockIdx.x;
    const int tid = threadIdx.x;
    const int lane = tid & 63;
    const int w = tid >> 6;
    const int i0 = w * IPW;
    const float* pb = pot + (size_t)b * TT * KK;

    {
        const float* g0 = pb + (w * 8) * KK;
        float* l0 = &stage[0][w * 8 * KK];
        gl_lds16(g0 + lane * 4, l0);
        gl_lds16(g0 + 256 + lane * 4, l0 + 256);
        const float* g1 = pb + (32 + w * 8) * KK;
        float* l1 = &stage[1][w * 8 * KK];
        gl_lds16(g1 + lane * 4, l1);
        gl_lds16(g1 + 256 + lane * 4, l1 + 256);
    }

    int cnt = 0;
    {
        const float4* p4 = (const float4*)pb;
        #pragma unroll 8
        for (int r = 0; r < 32; ++r) {
            float4 v = p4[tid + 256 * r];
            cnt += (v.x != 0.f) + (v.y != 0.f) + (v.z != 0.f) + (v.w != 0.f);
        }
        #pragma unroll
        for (int off = 32; off > 0; off >>= 1) cnt += __shfl_down(cnt, off, 64);
        if (lane == 0) wsum[w] = cnt;
        BARRIER();
    }
    const int seqlen = (wsum[0] + wsum[1] + wsum[2] + wsum[3]) >> 6;

    float tc[IPW];
    #pragma unroll
    for (int q = 0; q < IPW; ++q) tc[q] = trans[(i0 + q) * KK + lane];

    float alpha = pb[lane];

    WAIT_VM0();
    BARRIER();

    for (int t = 1; t < TT; ++t) {
        if ((t & 31) == 0) {
            WAIT_VM0();
            BARRIER();
            const int cn = (t >> 5) + 1;
            if (cn < 16) {
                const float* g0 = pb + (cn * 32 + w * 8) * KK;
                float* l0 = &stage[cn & 1][w * 8 * KK];
                gl_lds16(g0 + lane * 4, l0);
                gl_lds16(g0 + 256 + lane * 4, l0 + 256);
            }
        }
        const float ptj = stage[(t >> 5) & 1][(t & 31) * KK + lane];

        float m[4]; int am[4];
        #pragma unroll
        for (int c = 0; c < 4; ++c) {
            const int base = i0 + c * 4;
            float ai = __int_as_float(__builtin_amdgcn_readlane(__float_as_int(alpha), base));
            m[c] = ai + tc[c * 4];
            am[c] = base;
            #pragma unroll
            for (int qq = 1; qq < 4; ++qq) {
                const int iq = base + qq;
                float aq = __int_as_float(__builtin_amdgcn_readlane(__float_as_int(alpha), iq));
                float s = aq + tc[c * 4 + qq];
                bool g = s > m[c];
                m[c] = g ? s : m[c];
                am[c] = g ? iq : am[c];
            }
        }
        bool g01 = m[1] > m[0]; float m01 = g01 ? m[1] : m[0]; int a01 = g01 ? am[1] : am[0];
        bool g23 = m[3] > m[2]; float m23 = g23 ? m[3] : m[2]; int a23 = g23 ? am[3] : am[2];
        bool gg  = m23 > m01;  float mw  = gg ? m23 : m01;    int aw  = gg ? a23 : a01;

        const int buf = t & 1;
        ex[buf][w][lane] = make_int2(__float_as_int(mw), aw);
        BARRIER();
        const int2 e0 = ex[buf][0][lane], e1 = ex[buf][1][lane];
        const int2 e2 = ex[buf][2][lane], e3 = ex[buf][3][lane];
        const float f0 = __int_as_float(e0.x), f1 = __int_as_float(e1.x);
        const float f2 = __int_as_float(e2.x), f3 = __int_as_float(e3.x);
        bool h01 = f1 > f0; float p01 = h01 ? f1 : f0; int q01 = h01 ? e1.y : e0.y;
        bool h23 = f3 > f2; float p23 = h23 ? f3 : f2; int q23 = h23 ? e3.y : e2.y;
        bool hh  = p23 > p01; float M = hh ? p23 : p01; int BI = hh ? q23 : q01;

        const bool valid = (t < seqlen);
        alpha = valid ? (ptj + M) : alpha;
        if (w == (t & 3)) bp[t][lane] = (unsigned char)(valid ? BI : lane);
    }

    BARRIER();

    if (w == 0) {
        float v = alpha; int idx = lane;
        #pragma unroll
        for (int off = 1; off < 64; off <<= 1) {
            float vo = __shfl_xor(v, off, 64);
            int io  = __shfl_xor(idx, off, 64);
            bool take = (vo > v) || (vo == v && io < idx);
            v = take ? vo : v;
            idx = take ? io : idx;
        }
        const int last_tag = idx;

        int cur[64];
        #pragma unroll
        for (int s = 0; s < 64; ++s) cur[s] = lane;
        #pragma unroll
        for (int h = 8; h >= 1; --h) {
            #pragma unroll
            for (int s = 0; s < 64; ++s) {
                if (h == 8 && s == 63) continue;
                cur[s] = bp[8 * s + h][cur[s]];
            }
        }
        int tag = last_tag;
        bnd[63] = (unsigned char)last_tag;
        #pragma unroll
        for (int s = 63; s >= 1; --s) {
            tag = __builtin_amdgcn_readlane(cur[s], tag);
            bnd[s - 1] = (unsigned char)tag;
        }
        int cc = bnd[lane];
        const int t0 = lane * 8;
        int* ob = out + b * TT;
        if (lane == 63) ob[TT - 1] = last_tag;
        if (lane < 63) {
            cc = bp[t0 + 8][cc];
            ob[t0 + 7] = cc;
        }
        #pragma unroll
        for (int h = 7; h >= 1; --h) {
            cc = bp[t0 + h][cc];
            ob[t0 + h - 1] = cc;
        }
    }
}

extern "C" void kernel_launch(void* const* d_in, const int* in_sizes, int n_in,
                              void* d_out, int out_size, void* d_ws, size_t ws_size,
                              hipStream_t stream) {
    const float* inp = (const float*)d_in[0];     // [B, T, K] fp32
    const float* trans = (const float*)d_in[1];   // [K, K] fp32
    int* out = (int*)d_out;                       // [B, T] int32

    const size_t histBytes = (size_t)BB * TT * KK * sizeof(float);  // 64 MB
    if (ws_size >= histBytes + 2048) {
        float* alphaH = (float*)d_ws;
        int* seq = (int*)((char*)d_ws + histBytes);
        seqlen_kernel<<<BB, 256, 0, stream>>>(inp, seq);
        fwd_kernel<<<BB / 2, 128, 0, stream>>>(inp, trans, seq, alphaH, out);
    } else {
        crf_kernel<<<BB, 256, 0, stream>>>(inp, trans, out);  // proven fallback
    }
}